// Round 1
// baseline (366.353 us; speedup 1.0000x reference)
//
#include <hip/hip_runtime.h>
#include <stdint.h>

// Problem constants (from reference)
#define BATCH   2048
#define IN_BITS 4096
#define N_IN    2048
#define N_ST    1024
#define N_OUT   1024
#define KBITS   14
#define MW      512   // 2^14 bits / 32 = words per packed mem row
#define SROW    96    // s_inp/o_inp packed row words: 3072 bits = 64 (h_in) + 32 (state/s_out)

// ---------------------------------------------------------------------------
// Pack an int32 0/1 matrix into bitset rows. One thread -> one uint32 word
// (reads 32 ints as 8 x int4, sequential 128B per thread).
__global__ __launch_bounds__(256) void pack_i32(const int* __restrict__ src,
                                                uint32_t* __restrict__ dst,
                                                int total_words, int wshift,
                                                int dst_stride, int dst_off) {
    int t = blockIdx.x * 256 + threadIdx.x;
    if (t >= total_words) return;
    int r = t >> wshift;
    int c = t & ((1 << wshift) - 1);
    const int4* p = (const int4*)(src + ((long)r << (wshift + 5)) + (c << 5));
    uint32_t w = 0;
#pragma unroll
    for (int j = 0; j < 8; j++) {
        int4 v = p[j];
        w |= (uint32_t)(v.x == 1) << (4 * j + 0);
        w |= (uint32_t)(v.y == 1) << (4 * j + 1);
        w |= (uint32_t)(v.z == 1) << (4 * j + 2);
        w |= (uint32_t)(v.w == 1) << (4 * j + 3);
    }
    dst[(long)r * dst_stride + dst_off + c] = w;
}

// Pack a float mem table into "is TRUE (==1.0f)" bitset. Rows are contiguous
// and M%32==0, so treat flat.
__global__ __launch_bounds__(256) void pack_f32(const float* __restrict__ src,
                                                uint32_t* __restrict__ dst,
                                                int total_words) {
    int t = blockIdx.x * 256 + threadIdx.x;
    if (t >= total_words) return;
    const float4* p = (const float4*)(src + (long)t * 32);
    uint32_t w = 0;
#pragma unroll
    for (int j = 0; j < 8; j++) {
        float4 v = p[j];
        w |= (uint32_t)(v.x == 1.0f) << (4 * j + 0);
        w |= (uint32_t)(v.y == 1.0f) << (4 * j + 1);
        w |= (uint32_t)(v.z == 1.0f) << (4 * j + 2);
        w |= (uint32_t)(v.w == 1.0f) << (4 * j + 3);
    }
    dst[t] = w;
}

// ---------------------------------------------------------------------------
// RAM layer: lane = neuron (64 consecutive per wave), block stages BCHUNK
// packed batch rows in LDS. Per (b,n): gather 14 bits from LDS -> 14-bit
// address (k=0 is MSB per reference weights) -> 1 gather into packed mem row.
// MODE 0: write ballot bits to dst0 and dst1 at word offset 0 (stride SROW)
// MODE 1: write ballot bits to dst0 at word offset 64 (stride SROW)
// MODE 2: write floats to fout [b*N_OUT + n]
template <int SRCW, int BCHUNK, int MODE>
__global__ __launch_bounds__(256) void ram_layer(const uint32_t* __restrict__ src,
                                                 const int* __restrict__ conn,
                                                 const uint32_t* __restrict__ memp,
                                                 uint32_t* __restrict__ dst0,
                                                 uint32_t* __restrict__ dst1,
                                                 float* __restrict__ fout) {
    __shared__ uint32_t lds[BCHUNK * SRCW];
    const int tid = threadIdx.x;
    const int b0 = blockIdx.y * BCHUNK;

    // Stage BCHUNK contiguous packed rows (row stride == SRCW words, no pad).
    {
        const uint4* g = (const uint4*)(src + (long)b0 * SRCW);
        uint4* l = (uint4*)lds;
        constexpr int NV = BCHUNK * SRCW / 4;
        for (int i = tid; i < NV; i += 256) l[i] = g[i];
    }
    __syncthreads();

    const int n = blockIdx.x * 256 + tid;
    int wd[KBITS], sh[KBITS];
#pragma unroll
    for (int k = 0; k < KBITS; k++) {
        int idx = conn[n * KBITS + k];
        wd[k] = idx >> 5;
        sh[k] = idx & 31;
    }
    const uint32_t* mrow = memp + (long)n * MW;
    const int lane = tid & 63;
    const int nbase = blockIdx.x * 256 + (tid & ~63);  // wave's neuron base

#pragma unroll 4
    for (int bb = 0; bb < BCHUNK; ++bb) {
        const uint32_t* row = lds + bb * SRCW;
        uint32_t addr = 0;
#pragma unroll
        for (int k = 0; k < KBITS; k++)
            addr = (addr << 1) | ((row[wd[k]] >> sh[k]) & 1u);
        uint32_t bit = (mrow[addr >> 5] >> (addr & 31)) & 1u;
        const int b = b0 + bb;
        if (MODE == 2) {
            fout[(long)b * N_OUT + n] = (float)bit;
        } else {
            unsigned long long m = __ballot(bit != 0);
            if (lane == 0) {
                if (MODE == 0) {
                    *(unsigned long long*)(dst0 + (long)b * SROW + (nbase >> 5)) = m;
                    *(unsigned long long*)(dst1 + (long)b * SROW + (nbase >> 5)) = m;
                } else {
                    *(unsigned long long*)(dst0 + (long)b * SROW + 64 + (nbase >> 5)) = m;
                }
            }
        }
    }
}

// ---------------------------------------------------------------------------
extern "C" void kernel_launch(void* const* d_in, const int* in_sizes, int n_in,
                              void* d_out, int out_size, void* d_ws, size_t ws_size,
                              hipStream_t stream) {
    const int*   input_bits = (const int*)d_in[0];
    const int*   state_bits = (const int*)d_in[1];
    const int*   in_conn    = (const int*)d_in[2];
    const float* in_mem     = (const float*)d_in[3];
    const int*   st_conn    = (const int*)d_in[4];
    const float* st_mem     = (const float*)d_in[5];
    const int*   out_conn   = (const int*)d_in[6];
    const float* out_mem    = (const float*)d_in[7];
    float*       out        = (float*)d_out;

    // Workspace layout (all 256B-aligned):
    //   bits1 : [B][128] u32  = 1 MB   (packed input_bits)
    //   buf_s : [B][96]  u32  = 768 KB (s_inp bits: h_in | state)
    //   buf_o : [B][96]  u32  = 768 KB (o_inp bits: h_in | s_out)
    //   im_p  : [2048][512]   = 4 MB
    //   sm_p  : [1024][512]   = 2 MB
    //   om_p  : [1024][512]   = 2 MB
    char* ws = (char*)d_ws;
    uint32_t* bits1 = (uint32_t*)(ws);
    uint32_t* buf_s = (uint32_t*)(ws + 1048576);
    uint32_t* buf_o = (uint32_t*)(ws + 1048576 + 786432);
    uint32_t* im_p  = (uint32_t*)(ws + 1048576 + 2 * 786432);
    uint32_t* sm_p  = (uint32_t*)(ws + 1048576 + 2 * 786432 + 4194304);
    uint32_t* om_p  = (uint32_t*)(ws + 1048576 + 2 * 786432 + 4194304 + 2097152);

    // Bit-pack inputs and mem tables.
    pack_i32<<<(BATCH * 128 + 255) / 256, 256, 0, stream>>>(input_bits, bits1,
                                                            BATCH * 128, 7, 128, 0);
    pack_i32<<<(BATCH * 32 + 255) / 256, 256, 0, stream>>>(state_bits, buf_s,
                                                           BATCH * 32, 5, SROW, 64);
    pack_f32<<<(N_IN * MW + 255) / 256, 256, 0, stream>>>(in_mem, im_p, N_IN * MW);
    pack_f32<<<(N_ST * MW + 255) / 256, 256, 0, stream>>>(st_mem, sm_p, N_ST * MW);
    pack_f32<<<(N_OUT * MW + 255) / 256, 256, 0, stream>>>(out_mem, om_p, N_OUT * MW);

    // Layer 1: input_bits -> h_in (written into both buf_s and buf_o, words 0..63)
    ram_layer<128, 16, 0><<<dim3(N_IN / 256, BATCH / 16), 256, 0, stream>>>(
        bits1, in_conn, im_p, buf_s, buf_o, nullptr);
    // Layer 2: s_inp -> s_out (into buf_o words 64..95)
    ram_layer<SROW, 8, 1><<<dim3(N_ST / 256, BATCH / 8), 256, 0, stream>>>(
        buf_s, st_conn, sm_p, buf_o, nullptr, nullptr);
    // Layer 3: o_inp -> output floats
    ram_layer<SROW, 8, 2><<<dim3(N_OUT / 256, BATCH / 8), 256, 0, stream>>>(
        buf_o, out_conn, om_p, nullptr, nullptr, out);
}

// Round 2
// 348.017 us; speedup vs baseline: 1.0527x; 1.0527x over previous
//
#include <hip/hip_runtime.h>
#include <stdint.h>

// Problem constants (from reference)
#define BATCH   2048
#define IN_BITS 4096
#define N_IN    2048
#define N_ST    1024
#define N_OUT   1024
#define KBITS   14
#define MW      512   // 2^14 bits / 32 = words per packed mem row
#define SROW    96    // s_inp/o_inp packed row words: 3072 bits = 64 (h_in) + 32 (state/s_out)

// float4 counts per mem table
#define IM4 8388608   // N_IN * 16384 / 4
#define SM4 4194304   // N_ST * 16384 / 4
#define OM4 4194304

// ---------------------------------------------------------------------------
// Coalesced bit-pack of all three mem tables in one launch.
// Thread t loads ONE float4 at consecutive addresses (64 lanes -> 1KB
// contiguous per instruction), makes a 4-bit nibble (val==1.0f), then an
// 8-lane shfl-xor OR-reduction assembles 8 u32 words per wave.
__global__ __launch_bounds__(256) void pack_mem_all(const float4* __restrict__ im,
                                                    const float4* __restrict__ sm,
                                                    const float4* __restrict__ om,
                                                    uint32_t* __restrict__ im_p,
                                                    uint32_t* __restrict__ sm_p,
                                                    uint32_t* __restrict__ om_p) {
    int t = blockIdx.x * 256 + threadIdx.x;
    const float4* s;
    uint32_t* d;
    int local;
    if (t < IM4)            { s = im; d = im_p; local = t; }
    else if (t < IM4 + SM4) { s = sm; d = sm_p; local = t - IM4; }
    else                    { s = om; d = om_p; local = t - (IM4 + SM4); }
    float4 v = s[local];
    uint32_t nib = (uint32_t)(v.x == 1.0f) | ((uint32_t)(v.y == 1.0f) << 1) |
                   ((uint32_t)(v.z == 1.0f) << 2) | ((uint32_t)(v.w == 1.0f) << 3);
    int lane = threadIdx.x & 63;
    uint32_t w = nib << (4 * (lane & 7));
    w |= __shfl_xor(w, 1, 64);
    w |= __shfl_xor(w, 2, 64);
    w |= __shfl_xor(w, 4, 64);
    if ((lane & 7) == 0) d[local >> 3] = w;
}

// Coalesced pack of input_bits (dst rows contiguous, 128 words/row -> flat).
__global__ __launch_bounds__(256) void pack_input(const int4* __restrict__ src,
                                                  uint32_t* __restrict__ dst) {
    int t = blockIdx.x * 256 + threadIdx.x;  // one int4 (4 bits) per thread
    int4 v = src[t];
    uint32_t nib = (uint32_t)(v.x == 1) | ((uint32_t)(v.y == 1) << 1) |
                   ((uint32_t)(v.z == 1) << 2) | ((uint32_t)(v.w == 1) << 3);
    int lane = threadIdx.x & 63;
    uint32_t w = nib << (4 * (lane & 7));
    w |= __shfl_xor(w, 1, 64);
    w |= __shfl_xor(w, 2, 64);
    w |= __shfl_xor(w, 4, 64);
    if ((lane & 7) == 0) dst[t >> 3] = w;
}

// Coalesced pack of state_bits into buf_s at word offset 64, row stride SROW.
__global__ __launch_bounds__(256) void pack_state(const int4* __restrict__ src,
                                                  uint32_t* __restrict__ dst) {
    int t = blockIdx.x * 256 + threadIdx.x;  // one int4 per thread; row = 1024 bits
    int4 v = src[t];
    uint32_t nib = (uint32_t)(v.x == 1) | ((uint32_t)(v.y == 1) << 1) |
                   ((uint32_t)(v.z == 1) << 2) | ((uint32_t)(v.w == 1) << 3);
    int lane = threadIdx.x & 63;
    uint32_t w = nib << (4 * (lane & 7));
    w |= __shfl_xor(w, 1, 64);
    w |= __shfl_xor(w, 2, 64);
    w |= __shfl_xor(w, 4, 64);
    if ((lane & 7) == 0) {
        int g = t >> 3;          // global word index
        int r = g >> 5;          // 32 words per row
        int c = g & 31;
        dst[(long)r * SROW + 64 + c] = w;
    }
}

// ---------------------------------------------------------------------------
// RAM layer: lane = neuron (64 consecutive per wave), block stages BCHUNK
// packed batch rows in LDS. Per (b,n): gather 14 bits from LDS -> 14-bit
// address (k=0 is MSB per reference weights) -> 1 gather into packed mem row.
// MODE 0: write ballot bits to dst0 and dst1 at word offset 0 (stride SROW)
// MODE 1: write ballot bits to dst0 at word offset 64 (stride SROW)
// MODE 2: write floats to fout [b*N_OUT + n]
template <int SRCW, int BCHUNK, int MODE>
__global__ __launch_bounds__(256) void ram_layer(const uint32_t* __restrict__ src,
                                                 const int* __restrict__ conn,
                                                 const uint32_t* __restrict__ memp,
                                                 uint32_t* __restrict__ dst0,
                                                 uint32_t* __restrict__ dst1,
                                                 float* __restrict__ fout) {
    __shared__ uint32_t lds[BCHUNK * SRCW];
    const int tid = threadIdx.x;
    const int b0 = blockIdx.y * BCHUNK;

    // Stage BCHUNK contiguous packed rows (row stride == SRCW words, no pad).
    {
        const uint4* g = (const uint4*)(src + (long)b0 * SRCW);
        uint4* l = (uint4*)lds;
        constexpr int NV = BCHUNK * SRCW / 4;
        for (int i = tid; i < NV; i += 256) l[i] = g[i];
    }
    __syncthreads();

    const int n = blockIdx.x * 256 + tid;
    int wd[KBITS], sh[KBITS];
#pragma unroll
    for (int k = 0; k < KBITS; k++) {
        int idx = conn[n * KBITS + k];
        wd[k] = idx >> 5;
        sh[k] = idx & 31;
    }
    const uint32_t* mrow = memp + (long)n * MW;
    const int lane = tid & 63;
    const int nbase = blockIdx.x * 256 + (tid & ~63);  // wave's neuron base

#pragma unroll 4
    for (int bb = 0; bb < BCHUNK; ++bb) {
        const uint32_t* row = lds + bb * SRCW;
        uint32_t addr = 0;
#pragma unroll
        for (int k = 0; k < KBITS; k++)
            addr = (addr << 1) | ((row[wd[k]] >> sh[k]) & 1u);
        uint32_t bit = (mrow[addr >> 5] >> (addr & 31)) & 1u;
        const int b = b0 + bb;
        if (MODE == 2) {
            fout[(long)b * N_OUT + n] = (float)bit;
        } else {
            unsigned long long m = __ballot(bit != 0);
            if (lane == 0) {
                if (MODE == 0) {
                    *(unsigned long long*)(dst0 + (long)b * SROW + (nbase >> 5)) = m;
                    *(unsigned long long*)(dst1 + (long)b * SROW + (nbase >> 5)) = m;
                } else {
                    *(unsigned long long*)(dst0 + (long)b * SROW + 64 + (nbase >> 5)) = m;
                }
            }
        }
    }
}

// ---------------------------------------------------------------------------
extern "C" void kernel_launch(void* const* d_in, const int* in_sizes, int n_in,
                              void* d_out, int out_size, void* d_ws, size_t ws_size,
                              hipStream_t stream) {
    const int*   input_bits = (const int*)d_in[0];
    const int*   state_bits = (const int*)d_in[1];
    const int*   in_conn    = (const int*)d_in[2];
    const float* in_mem     = (const float*)d_in[3];
    const int*   st_conn    = (const int*)d_in[4];
    const float* st_mem     = (const float*)d_in[5];
    const int*   out_conn   = (const int*)d_in[6];
    const float* out_mem    = (const float*)d_in[7];
    float*       out        = (float*)d_out;

    // Workspace layout (all 256B-aligned):
    //   bits1 : [B][128] u32  = 1 MB   (packed input_bits)
    //   buf_s : [B][96]  u32  = 768 KB (s_inp bits: h_in | state)
    //   buf_o : [B][96]  u32  = 768 KB (o_inp bits: h_in | s_out)
    //   im_p  : [2048][512]   = 4 MB
    //   sm_p  : [1024][512]   = 2 MB
    //   om_p  : [1024][512]   = 2 MB
    char* ws = (char*)d_ws;
    uint32_t* bits1 = (uint32_t*)(ws);
    uint32_t* buf_s = (uint32_t*)(ws + 1048576);
    uint32_t* buf_o = (uint32_t*)(ws + 1048576 + 786432);
    uint32_t* im_p  = (uint32_t*)(ws + 1048576 + 2 * 786432);
    uint32_t* sm_p  = (uint32_t*)(ws + 1048576 + 2 * 786432 + 4194304);
    uint32_t* om_p  = (uint32_t*)(ws + 1048576 + 2 * 786432 + 4194304 + 2097152);

    // Bit-pack inputs (coalesced + wave shfl assembly).
    pack_input<<<(BATCH * IN_BITS / 4) / 256, 256, 0, stream>>>((const int4*)input_bits, bits1);
    pack_state<<<(BATCH * N_ST / 4) / 256, 256, 0, stream>>>((const int4*)state_bits, buf_s);
    pack_mem_all<<<(IM4 + SM4 + OM4) / 256, 256, 0, stream>>>(
        (const float4*)in_mem, (const float4*)st_mem, (const float4*)out_mem,
        im_p, sm_p, om_p);

    // Layer 1: input_bits -> h_in (written into both buf_s and buf_o, words 0..63)
    ram_layer<128, 16, 0><<<dim3(N_IN / 256, BATCH / 16), 256, 0, stream>>>(
        bits1, in_conn, im_p, buf_s, buf_o, nullptr);
    // Layer 2: s_inp -> s_out (into buf_o words 64..95)
    ram_layer<SROW, 8, 1><<<dim3(N_ST / 256, BATCH / 8), 256, 0, stream>>>(
        buf_s, st_conn, sm_p, buf_o, nullptr, nullptr);
    // Layer 3: o_inp -> output floats
    ram_layer<SROW, 8, 2><<<dim3(N_OUT / 256, BATCH / 8), 256, 0, stream>>>(
        buf_o, out_conn, om_p, nullptr, nullptr, out);
}